// Round 4
// baseline (158.030 us; speedup 1.0000x reference)
//
#include <hip/hip_runtime.h>
#include <hip/hip_bf16.h>
#include <stdint.h>

#define B_DIM 32
#define I_DIM 2048
#define J_DIM 2048
#define K_DIM 128

typedef __attribute__((ext_vector_type(8))) short bf16x8;
typedef __attribute__((ext_vector_type(4))) short short4v;
typedef __attribute__((ext_vector_type(4))) float f32x4;

__device__ inline short f2bf(float f) {
  union { float f; uint32_t u; } v; v.f = f;
  uint32_t u = v.u + 0x7fffu + ((v.u >> 16) & 1u);  // RNE
  return (short)(u >> 16);
}

// ---------------- pass 1a: A fp32 [b][i][k] -> bf16 (same layout) ----------------
__global__ __launch_bounds__(256) void convA_kernel(const float* __restrict__ A,
                                                    short* __restrict__ Ab) {
  const int idx = blockIdx.x * 256 + threadIdx.x;     // 8 elements each
  const float4* p = reinterpret_cast<const float4*>(A) + (size_t)idx * 2;
  const float4 a = p[0], b = p[1];
  bf16x8 o;
  o[0] = f2bf(a.x); o[1] = f2bf(a.y); o[2] = f2bf(a.z); o[3] = f2bf(a.w);
  o[4] = f2bf(b.x); o[5] = f2bf(b.y); o[6] = f2bf(b.z); o[7] = f2bf(b.w);
  reinterpret_cast<bf16x8*>(Ab)[idx] = o;
}

// ---------------- pass 1b: B fp32 [b][k][j] -> Bt bf16 [b][j][k] ----------------
__global__ __launch_bounds__(256) void transB_kernel(const float* __restrict__ B,
                                                     short* __restrict__ Bt) {
  __shared__ __align__(16) short tile[64 * 128];
  const int t  = threadIdx.x;
  const int j0 = blockIdx.x * 64;
  const int b  = blockIdx.y;
  const float* Bb = B + (size_t)b * K_DIM * J_DIM;
  const int jj = t & 63, kq = t >> 6;
  #pragma unroll
  for (int kr = 0; kr < 32; ++kr) {
    const int k = kr * 4 + kq;
    const float v = Bb[(size_t)k * J_DIM + j0 + jj];
    tile[jj * 128 + (k ^ ((jj & 15) << 3))] = f2bf(v);
  }
  __syncthreads();
  short* Btb = Bt + (size_t)b * J_DIM * K_DIM;
  const int slot = t & 15, jr = t >> 4;
  #pragma unroll
  for (int r2 = 0; r2 < 4; ++r2) {
    const int j  = r2 * 16 + jr;
    const bf16x8 v = *reinterpret_cast<const bf16x8*>(&tile[j * 128 + slot * 8]);
    const int k0 = (slot * 8) ^ ((j & 15) << 3);
    *reinterpret_cast<bf16x8*>(Btb + (size_t)(j0 + j) * K_DIM + k0) = v;
  }
}

// ---------------- pass 2: bf16 GEMM, 128x128 tile, BK=64, global_load_lds ----------------
#define GLD_LDS16(g, l) __builtin_amdgcn_global_load_lds( \
    (const __attribute__((address_space(1))) uint32_t*)(g), \
    (__attribute__((address_space(3))) uint32_t*)(l), 16, 0, 0)

__global__ __launch_bounds__(256, 4) void gemm_kernel(const short* __restrict__ Ab,
                                                      const short* __restrict__ Bt,
                                                      float* __restrict__ C) {
  __shared__ __align__(16) char smem[32768];
  short* As = (short*)smem;              // 16 KB [128 r][64 k] bf16, swizzled
  short* Bs = (short*)(smem + 16384);    // 16 KB
  float* Cs = (float*)smem;              // 32 KB epilogue half-tile [64][128] fp32

  const int t  = threadIdx.x;
  const int jt = blockIdx.x, it = blockIdx.y, b = blockIdx.z;

  const int rsub  = t >> 3;                                   // 0..31
  const int kbyte = ((t & 7) << 4) ^ ((rsub & 7) << 4);       // pre-swizzled source
  const char* Asrc = (const char*)(Ab + (size_t)(b * I_DIM + it * 128 + rsub) * K_DIM) + kbyte;
  const char* Bsrc = (const char*)(Bt + (size_t)(b * J_DIM + jt * 128 + rsub) * K_DIM) + kbyte;
  char* Adst = (char*)As + (t >> 6) * 1024;
  char* Bdst = (char*)Bs + (t >> 6) * 1024;

  const int w = t >> 6, wm = w >> 1, wn = w & 1;
  const int lane = t & 63, lr = lane & 15, g = lane >> 4;
  const int swr = (lr & 7) << 4;

  f32x4 acc[4][4];
  #pragma unroll
  for (int m = 0; m < 4; ++m)
    #pragma unroll
    for (int n = 0; n < 4; ++n)
      acc[m][n] = (f32x4){0.f, 0.f, 0.f, 0.f};

  #pragma unroll
  for (int ki = 0; ki < 2; ++ki) {
    if (ki) __syncthreads();
    #pragma unroll
    for (int q = 0; q < 4; ++q) {
      GLD_LDS16(Asrc + q * 8192 + ki * 128, Adst + q * 4096);
      GLD_LDS16(Bsrc + q * 8192 + ki * 128, Bdst + q * 4096);
    }
    __syncthreads();
    #pragma unroll
    for (int kk = 0; kk < 2; ++kk) {
      bf16x8 af[4], bb[4];
      const int cb = kk * 64 + g * 16;
      #pragma unroll
      for (int m = 0; m < 4; ++m) {
        const int R = wm * 64 + m * 16 + lr;
        af[m] = *reinterpret_cast<const bf16x8*>((const char*)As + R * 128 + (cb ^ swr));
      }
      #pragma unroll
      for (int n = 0; n < 4; ++n) {
        const int R = wn * 64 + n * 16 + lr;
        bb[n] = *reinterpret_cast<const bf16x8*>((const char*)Bs + R * 128 + (cb ^ swr));
      }
      #pragma unroll
      for (int m = 0; m < 4; ++m)
        #pragma unroll
        for (int n = 0; n < 4; ++n)
          acc[m][n] = __builtin_amdgcn_mfma_f32_16x16x32_bf16(af[m], bb[n], acc[m][n], 0, 0, 0);
    }
  }

  // ---- epilogue: LDS transpose -> full-line dwordx4 C stores ----
  // Half h holds tile rows 64h..64h+63 (owned by waves with wm==h).
  // Cs swizzle (16B-granular, bank-conflict-free): dword = r*128 + (c ^ ((r&7)<<2)).
  float* Cb = C + (size_t)b * I_DIM * J_DIM;
  #pragma unroll
  for (int h = 0; h < 2; ++h) {
    __syncthreads();                     // prior LDS readers (MFMA frags / stores) done
    if (wm == h) {
      #pragma unroll
      for (int m = 0; m < 4; ++m)
        #pragma unroll
        for (int q = 0; q < 4; ++q) {
          const int r = m * 16 + g * 4 + q;          // 0..63 within half
          #pragma unroll
          for (int n = 0; n < 4; ++n) {
            const int c = wn * 64 + n * 16 + lr;
            Cs[r * 128 + (c ^ ((r & 7) << 2))] = acc[m][n][q];
          }
        }
    }
    __syncthreads();
    #pragma unroll
    for (int cc = 0; cc < 8; ++cc) {
      const int id  = cc * 256 + t;
      const int row = id >> 5;           // 0..63
      const int ch  = id & 31;           // 16B chunk within row
      const f32x4 v = *reinterpret_cast<const f32x4*>(
          &Cs[row * 128 + ((ch << 2) ^ ((row & 7) << 2))]);
      *reinterpret_cast<f32x4*>(
          Cb + (size_t)(it * 128 + h * 64 + row) * J_DIM + jt * 128 + ch * 4) = v;
    }
  }
}

// ---------------- fallback (used only if ws too small) ----------------
__device__ inline int swz_fb(int row, int kbyte) {
  return row * 128 + ((kbyte ^ ((row & 15) << 4)) >> 1);
}

__global__ __launch_bounds__(256, 2) void bmm_fallback(const float* __restrict__ A,
                                                       const float* __restrict__ Bm,
                                                       float* __restrict__ C) {
  __shared__ short As[128 * 128];
  __shared__ short Bs[128 * 128];
  const int t  = threadIdx.x;
  const int jt = blockIdx.x, it = blockIdx.y, b = blockIdx.z;
  const float* Abp = A  + (size_t)b * I_DIM * K_DIM;
  const float* Bbp = Bm + (size_t)b * K_DIM * J_DIM;
  {
    const int r0 = t >> 5;
    const int k0 = (t & 31) * 4;
    #pragma unroll 4
    for (int i8 = 0; i8 < 16; ++i8) {
      const int r = i8 * 8 + r0;
      const float4 v = *reinterpret_cast<const float4*>(
          Abp + (size_t)(it * 128 + r) * K_DIM + k0);
      short4v s; s.x = f2bf(v.x); s.y = f2bf(v.y); s.z = f2bf(v.z); s.w = f2bf(v.w);
      *reinterpret_cast<short4v*>(&As[swz_fb(r, 2 * k0)]) = s;
    }
  }
  {
    const int j  = t & 127;
    const int kq = (t >> 7) * 4;
    #pragma unroll 4
    for (int kb = 0; kb < 16; ++kb) {
      const int k0 = kb * 8 + kq;
      const float* p = Bbp + (size_t)k0 * J_DIM + jt * 128 + j;
      const float f0 = p[0], f1 = p[J_DIM], f2 = p[2 * J_DIM], f3 = p[3 * J_DIM];
      short4v s; s.x = f2bf(f0); s.y = f2bf(f1); s.z = f2bf(f2); s.w = f2bf(f3);
      *reinterpret_cast<short4v*>(&Bs[swz_fb(j, 2 * k0)]) = s;
    }
  }
  __syncthreads();
  const int w = t >> 6, wm = w >> 1, wn = w & 1;
  const int lane = t & 63, lr = lane & 15, g = lane >> 4;
  f32x4 acc[4][4];
  #pragma unroll
  for (int m = 0; m < 4; ++m)
    #pragma unroll
    for (int n = 0; n < 4; ++n) acc[m][n] = (f32x4){0.f, 0.f, 0.f, 0.f};
  #pragma unroll
  for (int kk = 0; kk < 4; ++kk) {
    bf16x8 af[4], bfr[4];
    const int kb = kk * 64 + g * 16;
    #pragma unroll
    for (int m = 0; m < 4; ++m) {
      const int r = wm * 64 + m * 16 + lr;
      af[m] = *reinterpret_cast<const bf16x8*>(&As[swz_fb(r, kb)]);
    }
    #pragma unroll
    for (int n = 0; n < 4; ++n) {
      const int r = wn * 64 + n * 16 + lr;
      bfr[n] = *reinterpret_cast<const bf16x8*>(&Bs[swz_fb(r, kb)]);
    }
    #pragma unroll
    for (int m = 0; m < 4; ++m)
      #pragma unroll
      for (int n = 0; n < 4; ++n)
        acc[m][n] = __builtin_amdgcn_mfma_f32_16x16x32_bf16(af[m], bfr[n], acc[m][n], 0, 0, 0);
  }
  float* Cb = C + (size_t)b * I_DIM * J_DIM;
  const int cbase = jt * 128 + wn * 64 + lr;
  #pragma unroll
  for (int m = 0; m < 4; ++m) {
    const int rbase = it * 128 + wm * 64 + m * 16 + g * 4;
    #pragma unroll
    for (int q = 0; q < 4; ++q) {
      float* crow = Cb + (size_t)(rbase + q) * J_DIM + cbase;
      #pragma unroll
      for (int n = 0; n < 4; ++n) crow[n * 16] = acc[m][n][q];
    }
  }
}

extern "C" void kernel_launch(void* const* d_in, const int* in_sizes, int n_in,
                              void* d_out, int out_size, void* d_ws, size_t ws_size,
                              hipStream_t stream) {
  const float* A  = (const float*)d_in[0];
  const float* Bm = (const float*)d_in[1];
  float* C = (float*)d_out;
  const size_t needA = (size_t)B_DIM * I_DIM * K_DIM * sizeof(short);  // 16 MiB
  const size_t needB = (size_t)B_DIM * K_DIM * J_DIM * sizeof(short);  // 16 MiB
  if (ws_size >= needA + needB) {
    short* Ab = (short*)d_ws;
    short* Bt = (short*)((char*)d_ws + needA);
    convA_kernel<<<4096, 256, 0, stream>>>(A, Ab);
    transB_kernel<<<dim3(J_DIM / 64, B_DIM), 256, 0, stream>>>(Bm, Bt);
    gemm_kernel<<<dim3(J_DIM / 128, I_DIM / 128, B_DIM), 256, 0, stream>>>(Ab, Bt, C);
  } else {
    bmm_fallback<<<dim3(J_DIM / 128, I_DIM / 128, B_DIM), 256, 0, stream>>>(A, Bm, C);
  }
}

// Round 5
// 147.547 us; speedup vs baseline: 1.0710x; 1.0710x over previous
//
#include <hip/hip_runtime.h>
#include <hip/hip_bf16.h>
#include <stdint.h>

#define B_DIM 32
#define I_DIM 2048
#define J_DIM 2048
#define K_DIM 128

typedef __attribute__((ext_vector_type(8))) short bf16x8;
typedef __attribute__((ext_vector_type(4))) short short4v;
typedef __attribute__((ext_vector_type(4))) float f32x4;

__device__ inline short f2bf(float f) {
  union { float f; uint32_t u; } v; v.f = f;
  uint32_t u = v.u + 0x7fffu + ((v.u >> 16) & 1u);  // RNE
  return (short)(u >> 16);
}

// ---------------- pass 1a: A fp32 [b][i][k] -> bf16 (same layout) ----------------
__global__ __launch_bounds__(256) void convA_kernel(const float* __restrict__ A,
                                                    short* __restrict__ Ab) {
  const int idx = blockIdx.x * 256 + threadIdx.x;     // 8 elements each
  const float4* p = reinterpret_cast<const float4*>(A) + (size_t)idx * 2;
  const float4 a = p[0], b = p[1];
  bf16x8 o;
  o[0] = f2bf(a.x); o[1] = f2bf(a.y); o[2] = f2bf(a.z); o[3] = f2bf(a.w);
  o[4] = f2bf(b.x); o[5] = f2bf(b.y); o[6] = f2bf(b.z); o[7] = f2bf(b.w);
  reinterpret_cast<bf16x8*>(Ab)[idx] = o;
}

// ---------------- pass 1b: B fp32 [b][k][j] -> Bt bf16 [b][j][k] ----------------
__global__ __launch_bounds__(256) void transB_kernel(const float* __restrict__ B,
                                                     short* __restrict__ Bt) {
  __shared__ __align__(16) short tile[64 * 128];
  const int t  = threadIdx.x;
  const int j0 = blockIdx.x * 64;
  const int b  = blockIdx.y;
  const float* Bb = B + (size_t)b * K_DIM * J_DIM;
  const int jj = t & 63, kq = t >> 6;
  #pragma unroll
  for (int kr = 0; kr < 32; ++kr) {
    const int k = kr * 4 + kq;
    const float v = Bb[(size_t)k * J_DIM + j0 + jj];
    tile[jj * 128 + (k ^ ((jj & 15) << 3))] = f2bf(v);
  }
  __syncthreads();
  short* Btb = Bt + (size_t)b * J_DIM * K_DIM;
  const int slot = t & 15, jr = t >> 4;
  #pragma unroll
  for (int r2 = 0; r2 < 4; ++r2) {
    const int j  = r2 * 16 + jr;
    const bf16x8 v = *reinterpret_cast<const bf16x8*>(&tile[j * 128 + slot * 8]);
    const int k0 = (slot * 8) ^ ((j & 15) << 3);
    *reinterpret_cast<bf16x8*>(Btb + (size_t)(j0 + j) * K_DIM + k0) = v;
  }
}

// ---------------- pass 2: bf16 GEMM, 128x128 tile, BK=64, global_load_lds ----------------
// Identical to round-3 gemm except: 1-D grid + bijective XCD swizzle so each
// XCD owns 4 whole batches (1 MB bf16 A+B per batch -> lives in that XCD's L2;
// the 16x tile re-reads become L2 hits instead of cross-XCD L3 traffic).
#define GLD_LDS16(g, l) __builtin_amdgcn_global_load_lds( \
    (const __attribute__((address_space(1))) uint32_t*)(g), \
    (__attribute__((address_space(3))) uint32_t*)(l), 16, 0, 0)

__global__ __launch_bounds__(256, 4) void gemm_kernel(const short* __restrict__ Ab,
                                                      const short* __restrict__ Bt,
                                                      float* __restrict__ C) {
  __shared__ __align__(16) short As[8192];   // [128 r][64 k] bf16, swizzled
  __shared__ __align__(16) short Bs[8192];
  const int t = threadIdx.x;

  // XCD swizzle: physical p -> logical lid; XCD x gets lid in [x*1024,(x+1)*1024)
  // = 4 complete batches. 8192 % 8 == 0 -> bijective.
  const int p   = blockIdx.x;
  const int lid = ((p & 7) << 10) | (p >> 3);
  const int jt  = lid & 15;
  const int it  = (lid >> 4) & 15;
  const int b   = lid >> 8;

  const int rsub  = t >> 3;                                   // 0..31
  const int kbyte = ((t & 7) << 4) ^ ((rsub & 7) << 4);       // pre-swizzled source
  const char* Asrc = (const char*)(Ab + (size_t)(b * I_DIM + it * 128 + rsub) * K_DIM) + kbyte;
  const char* Bsrc = (const char*)(Bt + (size_t)(b * J_DIM + jt * 128 + rsub) * K_DIM) + kbyte;
  char* Adst = (char*)As + (t >> 6) * 1024;   // wave-uniform base; HW adds lane*16
  char* Bdst = (char*)Bs + (t >> 6) * 1024;

  const int w = t >> 6, wm = w >> 1, wn = w & 1;
  const int lane = t & 63, lr = lane & 15, g = lane >> 4;
  const int swr = (lr & 7) << 4;              // read-side XOR

  f32x4 acc[4][4];
  #pragma unroll
  for (int m = 0; m < 4; ++m)
    #pragma unroll
    for (int n = 0; n < 4; ++n)
      acc[m][n] = (f32x4){0.f, 0.f, 0.f, 0.f};

  #pragma unroll
  for (int ki = 0; ki < 2; ++ki) {            // K = 2 x BK=64
    if (ki) __syncthreads();                  // drain reads before overwriting LDS
    #pragma unroll
    for (int q = 0; q < 4; ++q) {
      GLD_LDS16(Asrc + q * 8192 + ki * 128, Adst + q * 4096);
      GLD_LDS16(Bsrc + q * 8192 + ki * 128, Bdst + q * 4096);
    }
    __syncthreads();
    #pragma unroll
    for (int kk = 0; kk < 2; ++kk) {
      bf16x8 af[4], bb[4];
      const int cb = kk * 64 + g * 16;
      #pragma unroll
      for (int m = 0; m < 4; ++m) {
        const int R = wm * 64 + m * 16 + lr;
        af[m] = *reinterpret_cast<const bf16x8*>((const char*)As + R * 128 + (cb ^ swr));
      }
      #pragma unroll
      for (int n = 0; n < 4; ++n) {
        const int R = wn * 64 + n * 16 + lr;
        bb[n] = *reinterpret_cast<const bf16x8*>((const char*)Bs + R * 128 + (cb ^ swr));
      }
      #pragma unroll
      for (int m = 0; m < 4; ++m)
        #pragma unroll
        for (int n = 0; n < 4; ++n)
          acc[m][n] = __builtin_amdgcn_mfma_f32_16x16x32_bf16(af[m], bb[n], acc[m][n], 0, 0, 0);
    }
  }

  // C write: col = lane&15, row = g*4 + reg (round-3 direct-store path)
  float* Cb = C + (size_t)b * I_DIM * J_DIM;
  const int cbase = jt * 128 + wn * 64 + lr;
  #pragma unroll
  for (int m = 0; m < 4; ++m) {
    const int rbase = it * 128 + wm * 64 + m * 16 + g * 4;
    #pragma unroll
    for (int q = 0; q < 4; ++q) {
      float* crow = Cb + (size_t)(rbase + q) * J_DIM + cbase;
      #pragma unroll
      for (int n = 0; n < 4; ++n) crow[n * 16] = acc[m][n][q];
    }
  }
}

// ---------------- fallback (used only if ws too small) ----------------
__device__ inline int swz_fb(int row, int kbyte) {
  return row * 128 + ((kbyte ^ ((row & 15) << 4)) >> 1);
}

__global__ __launch_bounds__(256, 2) void bmm_fallback(const float* __restrict__ A,
                                                       const float* __restrict__ Bm,
                                                       float* __restrict__ C) {
  __shared__ short As[128 * 128];
  __shared__ short Bs[128 * 128];
  const int t  = threadIdx.x;
  const int jt = blockIdx.x, it = blockIdx.y, b = blockIdx.z;
  const float* Abp = A  + (size_t)b * I_DIM * K_DIM;
  const float* Bbp = Bm + (size_t)b * K_DIM * J_DIM;
  {
    const int r0 = t >> 5;
    const int k0 = (t & 31) * 4;
    #pragma unroll 4
    for (int i8 = 0; i8 < 16; ++i8) {
      const int r = i8 * 8 + r0;
      const float4 v = *reinterpret_cast<const float4*>(
          Abp + (size_t)(it * 128 + r) * K_DIM + k0);
      short4v s; s.x = f2bf(v.x); s.y = f2bf(v.y); s.z = f2bf(v.z); s.w = f2bf(v.w);
      *reinterpret_cast<short4v*>(&As[swz_fb(r, 2 * k0)]) = s;
    }
  }
  {
    const int j  = t & 127;
    const int kq = (t >> 7) * 4;
    #pragma unroll 4
    for (int kb = 0; kb < 16; ++kb) {
      const int k0 = kb * 8 + kq;
      const float* p = Bbp + (size_t)k0 * J_DIM + jt * 128 + j;
      const float f0 = p[0], f1 = p[J_DIM], f2 = p[2 * J_DIM], f3 = p[3 * J_DIM];
      short4v s; s.x = f2bf(f0); s.y = f2bf(f1); s.z = f2bf(f2); s.w = f2bf(f3);
      *reinterpret_cast<short4v*>(&Bs[swz_fb(j, 2 * k0)]) = s;
    }
  }
  __syncthreads();
  const int w = t >> 6, wm = w >> 1, wn = w & 1;
  const int lane = t & 63, lr = lane & 15, g = lane >> 4;
  f32x4 acc[4][4];
  #pragma unroll
  for (int m = 0; m < 4; ++m)
    #pragma unroll
    for (int n = 0; n < 4; ++n) acc[m][n] = (f32x4){0.f, 0.f, 0.f, 0.f};
  #pragma unroll
  for (int kk = 0; kk < 4; ++kk) {
    bf16x8 af[4], bfr[4];
    const int kb = kk * 64 + g * 16;
    #pragma unroll
    for (int m = 0; m < 4; ++m) {
      const int r = wm * 64 + m * 16 + lr;
      af[m] = *reinterpret_cast<const bf16x8*>(&As[swz_fb(r, kb)]);
    }
    #pragma unroll
    for (int n = 0; n < 4; ++n) {
      const int r = wn * 64 + n * 16 + lr;
      bfr[n] = *reinterpret_cast<const bf16x8*>(&Bs[swz_fb(r, kb)]);
    }
    #pragma unroll
    for (int m = 0; m < 4; ++m)
      #pragma unroll
      for (int n = 0; n < 4; ++n)
        acc[m][n] = __builtin_amdgcn_mfma_f32_16x16x32_bf16(af[m], bfr[n], acc[m][n], 0, 0, 0);
  }
  float* Cb = C + (size_t)b * I_DIM * J_DIM;
  const int cbase = jt * 128 + wn * 64 + lr;
  #pragma unroll
  for (int m = 0; m < 4; ++m) {
    const int rbase = it * 128 + wm * 64 + m * 16 + g * 4;
    #pragma unroll
    for (int q = 0; q < 4; ++q) {
      float* crow = Cb + (size_t)(rbase + q) * J_DIM + cbase;
      #pragma unroll
      for (int n = 0; n < 4; ++n) crow[n * 16] = acc[m][n][q];
    }
  }
}

extern "C" void kernel_launch(void* const* d_in, const int* in_sizes, int n_in,
                              void* d_out, int out_size, void* d_ws, size_t ws_size,
                              hipStream_t stream) {
  const float* A  = (const float*)d_in[0];
  const float* Bm = (const float*)d_in[1];
  float* C = (float*)d_out;
  const size_t needA = (size_t)B_DIM * I_DIM * K_DIM * sizeof(short);  // 16 MiB
  const size_t needB = (size_t)B_DIM * K_DIM * J_DIM * sizeof(short);  // 16 MiB
  if (ws_size >= needA + needB) {
    short* Ab = (short*)d_ws;
    short* Bt = (short*)((char*)d_ws + needA);
    convA_kernel<<<4096, 256, 0, stream>>>(A, Ab);
    transB_kernel<<<dim3(J_DIM / 64, B_DIM), 256, 0, stream>>>(Bm, Bt);
    gemm_kernel<<<8192, 256, 0, stream>>>(Ab, Bt, C);
  } else {
    bmm_fallback<<<dim3(J_DIM / 128, I_DIM / 128, B_DIM), 256, 0, stream>>>(A, Bm, C);
  }
}